// Round 14
// baseline (396.922 us; speedup 1.0000x reference)
//
#include <hip/hip_runtime.h>

// 2-layer LSTM (HID=10), B=2048, T=1024 main + F=64 future steps.
//
// Round 21: r17 2-wave structure (1 wave/SIMD) + DPP-ring recurrences.
// Ledger: r16/r17/r18/r20 (4 structures) all ~600-630 cyc/step => dur =
// T x serial chain; occupancy/issue/role-balance all null. Chain budget:
// dots ~50 + act (4 serial trans) ~150-200 + bcast10 (10 ds_swizzle,
// waited in-chain) ~150-200. The swizzle hop is the largest REMOVABLE
// term. r19's DPP attempt was confounded (2 waves/SIMD exec-sharing +
// doubled dot issue on both serial roles). Clean test: 1 wave/SIMD where
// extra issue is free and wall == chain.
//  - W0 (cell1+U): h1 kept rotated (h1r[16]); rot16 = 15 parallel
//    v_mov_dpp (~10 cyc chain); dots = 16-term pre-rotated masked tables
//    (r19-verified machinery, passed absmax 6.1e-5). U-dots also rotated
//    (off-chain, feeds ringU).
//  - W1 (cell2+head): same DPP form for the h2 recurrence; head via
//    rotated Wlin table (each lane gets the full sum, r11-verified).
//  - Future loop: r17's flat/swizzle fstep verbatim (flat tables built
//    after the main loop; bc16<0> makes yprev lane-uniform = stored y3).
// Structure (rings, barriers, handoffs, stores) verbatim r17.
// Falsification: dur 265-295 => chain is trans/dot-bound => declare floor.

#define NB 512
#define TMAIN 1024
#define HID 10
#define KCH 16
#define NCH (TMAIN / KCH)   // 64 chunks

typedef float v2f __attribute__((ext_vector_type(2)));
typedef float v4f __attribute__((ext_vector_type(4)));

#define PIN2(v) asm volatile("" : "+v"(v))
#define PIN(v)  asm volatile("" : "+v"(v))

__device__ __forceinline__ float rcp_(float v)  { return __builtin_amdgcn_rcpf(v); }
__device__ __forceinline__ float exp2_(float v) { return __builtin_amdgcn_exp2f(v); }
__device__ __forceinline__ v2f mk2(float x, float y) { v2f r; r.x = x; r.y = y; return r; }
__device__ __forceinline__ v2f pfma2(v2f a, v2f b, v2f c) { return __builtin_elementwise_fma(a, b, c); }

template<int R>
__device__ __forceinline__ float rorf(float v) {   // DPP row_ror:R (16-lane rows)
    return __int_as_float(__builtin_amdgcn_update_dpp(
        0, __float_as_int(v), 0x120 + R, 0xF, 0xF, true));
}
__device__ __forceinline__ void rot16(float h, float* hr) {
    hr[0] = h;
    hr[1]  = rorf<1>(h);  hr[2]  = rorf<2>(h);  hr[3]  = rorf<3>(h);
    hr[4]  = rorf<4>(h);  hr[5]  = rorf<5>(h);  hr[6]  = rorf<6>(h);
    hr[7]  = rorf<7>(h);  hr[8]  = rorf<8>(h);  hr[9]  = rorf<9>(h);
    hr[10] = rorf<10>(h); hr[11] = rorf<11>(h); hr[12] = rorf<12>(h);
    hr[13] = rorf<13>(h); hr[14] = rorf<14>(h); hr[15] = rorf<15>(h);
}
template<int J>
__device__ __forceinline__ float bc16(float v) {   // broadcast lane (grp|J) within 16-group
    return __int_as_float(__builtin_amdgcn_ds_swizzle(__float_as_int(v), (J << 5) | 0x10));
}
__device__ __forceinline__ void bcast10(float h, float* hb) {
    hb[0] = bc16<0>(h); hb[1] = bc16<1>(h); hb[2] = bc16<2>(h); hb[3] = bc16<3>(h);
    hb[4] = bc16<4>(h); hb[5] = bc16<5>(h); hb[6] = bc16<6>(h); hb[7] = bc16<7>(h);
    hb[8] = bc16<8>(h); hb[9] = bc16<9>(h);
}

__global__ __launch_bounds__(128)
void lstm2_kernel(
    const float* __restrict__ x,
    const float* __restrict__ Wih1, const float* __restrict__ Whh1,
    const float* __restrict__ bih1, const float* __restrict__ bhh1,
    const float* __restrict__ Wih2, const float* __restrict__ Whh2,
    const float* __restrict__ bih2, const float* __restrict__ bhh2,
    const float* __restrict__ Wlin, const float* __restrict__ blin,
    const int* __restrict__ futp,
    float* __restrict__ out)
{
    const int tid  = threadIdx.x;
    const int wid  = tid >> 6;           // 0 = cell1 producer, 1 = cell2+head consumer
    const int lane = tid & 63;
    const int e    = lane >> 4;          // element 0..3
    const int u    = lane & 15;          // unit (valid < 10)
    const int ge   = blockIdx.x * 4 + e;
    const int F    = futp[0];
    const int OUTW = TMAIN + F;

    __shared__ v4f   ringU[2][KCH][64];  // U(t)=Wih2*h1(t)+b2 pre-acts (i,f,g,o)
    __shared__ float stC1[64], stH1[64]; // final c1 / h1 handoff for future loop

    const bool uok = (u < HID);
    const int  uu  = uok ? u : 0;
    const int  Ri  = 0 * HID + uu;
    const int  Rf  = 1 * HID + uu;
    const int  Rg  = 2 * HID + uu;
    const int  Ro  = 3 * HID + uu;

    const float tK = 2.8853900817779268f;    //  2*log2(e)
    const float sK = -1.4426950408889634f;   // -log2(e)
    const float mu = uok ? 1.f : 0.f;
    const float sKm = mu * sK;
    const float tKm = mu * tK;

    // DPP direction probe (r11/r19-verified)
    const int rot1 = __builtin_amdgcn_update_dpp(0, u, 0x121, 0xF, 0xF, true);
    const bool dplus = (rot1 == ((u + 1) & 15));

    // ---- role-specific rotated tables (term r multiplies hr[r]) ----
    v2f wr1_if[16], wr1_go[16], wr2i_if[16], wr2i_go[16];   // W0
    v2f wr2h_if[16], wr2h_go[16];                           // W1
    float wlr[16];                                          // W1 head
    v2f wx_if = mk2(0.f, 0.f), wx_go = wx_if;
    v2f b1_if = wx_if, b1_go = wx_if, b2_if = wx_if, b2_go = wx_if;
    float bl = blin[0];

    if (wid == 0) {
        #pragma unroll
        for (int r = 0; r < 16; ++r) {
            int jr = (u + (dplus ? r : 16 - r)) & 15;
            int jc = (jr < HID) ? jr : 0;
            float m = (uok && jr < HID) ? 1.f : 0.f;
            wr1_if[r]  = mk2(m * sK * Whh1[Ri*HID + jc], m * sK * Whh1[Rf*HID + jc]);
            wr1_go[r]  = mk2(m * tK * Whh1[Rg*HID + jc], m * sK * Whh1[Ro*HID + jc]);
            wr2i_if[r] = mk2(m * sK * Wih2[Ri*HID + jc], m * sK * Wih2[Rf*HID + jc]);
            wr2i_go[r] = mk2(m * tK * Wih2[Rg*HID + jc], m * sK * Wih2[Ro*HID + jc]);
        }
        wx_if = mk2(sKm * Wih1[Ri], sKm * Wih1[Rf]);
        wx_go = mk2(tKm * Wih1[Rg], sKm * Wih1[Ro]);
        b1_if = mk2(sKm * (bih1[Ri] + bhh1[Ri]), sKm * (bih1[Rf] + bhh1[Rf]));
        b1_go = mk2(tKm * (bih1[Rg] + bhh1[Rg]), sKm * (bih1[Ro] + bhh1[Ro]));
        b2_if = mk2(sKm * (bih2[Ri] + bhh2[Ri]), sKm * (bih2[Rf] + bhh2[Rf]));
        b2_go = mk2(tKm * (bih2[Rg] + bhh2[Rg]), sKm * (bih2[Ro] + bhh2[Ro]));
        #pragma unroll
        for (int r = 0; r < 16; ++r) { PIN2(wr1_if[r]); PIN2(wr1_go[r]); PIN2(wr2i_if[r]); PIN2(wr2i_go[r]); }
        PIN2(wx_if); PIN2(wx_go); PIN2(b1_if); PIN2(b1_go); PIN2(b2_if); PIN2(b2_go);
    } else {
        #pragma unroll
        for (int r = 0; r < 16; ++r) {
            int jr = (u + (dplus ? r : 16 - r)) & 15;
            int jc = (jr < HID) ? jr : 0;
            float m = (uok && jr < HID) ? 1.f : 0.f;
            wr2h_if[r] = mk2(m * sK * Whh2[Ri*HID + jc], m * sK * Whh2[Rf*HID + jc]);
            wr2h_go[r] = mk2(m * tK * Whh2[Rg*HID + jc], m * sK * Whh2[Ro*HID + jc]);
            wlr[r]     = (jr < HID) ? Wlin[jc] : 0.f;
        }
        #pragma unroll
        for (int r = 0; r < 16; ++r) { PIN2(wr2h_if[r]); PIN2(wr2h_go[r]); PIN(wlr[r]); }
        PIN(bl);
    }

    auto ctanh_ = [&](float cs) -> float {       // tanh of (tK-scaled) cell state
        return fmaf(-2.0f, rcp_(1.0f + exp2_(cs)), 1.0f);
    };
    auto cellup2 = [&](v2f p_if, v2f p_go, float& c) -> float {   // verbatim r17
        v2f q_if, q_go;
        q_if.x = rcp_(1.0f + exp2_(p_if.x));     // i
        q_if.y = rcp_(1.0f + exp2_(p_if.y));     // f
        q_go.x = rcp_(1.0f + exp2_(p_go.x));     // g (pre-act)
        q_go.y = rcp_(1.0f + exp2_(p_go.y));     // o
        float g = fmaf(-2.0f * tK, q_go.x, tK);  // tK*tanh
        c = fmaf(q_if.y, c, q_if.x * g);         // f*c + i*g
        return q_go.y * ctanh_(c);               // o * tanh(c)
    };
    auto dot16rot = [&](const v2f* w, const float* hr, v2f init) -> v2f {
        v2f P = pfma2(w[0], mk2(hr[0], hr[0]), init);
        v2f Q = w[1] * mk2(hr[1], hr[1]);
        #pragma unroll
        for (int r = 2; r < 16; r += 2) {
            P = pfma2(w[r],     mk2(hr[r],     hr[r]),     P);
            Q = pfma2(w[r + 1], mk2(hr[r + 1], hr[r + 1]), Q);
        }
        return P + Q;
    };
    auto dotp = [&](const v2f* w, const float* hb, v2f init) -> v2f {  // flat 10-term
        v2f P = pfma2(w[0], mk2(hb[0], hb[0]), init);
        v2f Q = w[1] * mk2(hb[1], hb[1]);
        #pragma unroll
        for (int j = 2; j < HID; j += 2) {
            P = pfma2(w[j],     mk2(hb[j],     hb[j]),     P);
            Q = pfma2(w[j + 1], mk2(hb[j + 1], hb[j + 1]), Q);
        }
        return P + Q;
    };

    // ---- state ----
    float c1 = 0.f, c2 = 0.f, h1last = 0.f, yprev = 0.f;
    float h1r[16], h2r[16];
    #pragma unroll
    for (int r = 0; r < 16; ++r) { h1r[r] = 0.f; h2r[r] = 0.f; }

    auto head16 = [&]() -> float {               // rotated head: full sum on every lane
        float Y = fmaf(wlr[0], h2r[0], bl);
        float Z = wlr[1] * h2r[1];
        #pragma unroll
        for (int r = 2; r < 16; r += 2) {
            Y = fmaf(wlr[r],     h2r[r],     Y);
            Z = fmaf(wlr[r + 1], h2r[r + 1], Z);
        }
        return Y + Z;
    };

    // W0 step: cell1 (DPP recurrence) + U-dot -> ring slot
    auto pstep0 = [&](float xt, v4f* slot) -> float {
        v2f A_if = dot16rot(wr1_if, h1r, pfma2(wx_if, mk2(xt, xt), b1_if));
        v2f A_go = dot16rot(wr1_go, h1r, pfma2(wx_go, mk2(xt, xt), b1_go));
        float h1n = cellup2(A_if, A_go, c1);
        rot16(h1n, h1r);
        v2f U_if = dot16rot(wr2i_if, h1r, b2_if);
        v2f U_go = dot16rot(wr2i_go, h1r, b2_go);
        v4f U; U.x = U_if.x; U.y = U_if.y; U.z = U_go.x; U.w = U_go.y;
        slot[lane] = U;
        return h1n;
    };
    // W1 step: cell2 (DPP recurrence) from preloaded U, then y
    auto cstep = [&](v4f U) -> float {
        v2f V_if = dot16rot(wr2h_if, h2r, mk2(U.x, U.y));
        v2f V_go = dot16rot(wr2h_go, h2r, mk2(U.z, U.w));
        float h2n = cellup2(V_if, V_go, c2);
        rot16(h2n, h2r);
        return head16();
    };

    const float4* xrow = (const float4*)(x + (size_t)ge * TMAIN);
    float4* orow = (float4*)(out + (size_t)ge * OUTW);   // OUTW=1088, 16B rows

    float4 z4 = make_float4(0.f, 0.f, 0.f, 0.f);
    float4 xq0 = z4, xq1 = z4, xq2 = z4, xq3 = z4;
    if (wid == 0) { xq0 = xrow[0]; xq1 = xrow[1]; xq2 = xrow[2]; xq3 = xrow[3]; }

    // ---- main pipeline: 65 chunk-iterations, consumer one chunk behind ----
    #pragma unroll 1
    for (int c = 0; c <= NCH; ++c) {
        if (wid == 0) {
            if (c < NCH) {
                float4 xn0 = z4, xn1 = z4, xn2 = z4, xn3 = z4;
                if (c + 1 < NCH) {
                    xn0 = xrow[(c+1)*4+0]; xn1 = xrow[(c+1)*4+1];
                    xn2 = xrow[(c+1)*4+2]; xn3 = xrow[(c+1)*4+3];
                }
                v4f* rb = &ringU[c & 1][0][0];
                h1last = pstep0(xq0.x, rb + 0*64);  h1last = pstep0(xq0.y, rb + 1*64);
                h1last = pstep0(xq0.z, rb + 2*64);  h1last = pstep0(xq0.w, rb + 3*64);
                h1last = pstep0(xq1.x, rb + 4*64);  h1last = pstep0(xq1.y, rb + 5*64);
                h1last = pstep0(xq1.z, rb + 6*64);  h1last = pstep0(xq1.w, rb + 7*64);
                h1last = pstep0(xq2.x, rb + 8*64);  h1last = pstep0(xq2.y, rb + 9*64);
                h1last = pstep0(xq2.z, rb + 10*64); h1last = pstep0(xq2.w, rb + 11*64);
                h1last = pstep0(xq3.x, rb + 12*64); h1last = pstep0(xq3.y, rb + 13*64);
                h1last = pstep0(xq3.z, rb + 14*64); h1last = pstep0(xq3.w, rb + 15*64);
                if (c == NCH - 1) { stC1[lane] = c1; stH1[lane] = h1last; }
                xq0 = xn0; xq1 = xn1; xq2 = xn2; xq3 = xn3;
            }
        } else {
            if (c >= 1) {
                const v4f* rb = &ringU[(c - 1) & 1][0][0];
                #pragma unroll
                for (int q = 0; q < 4; ++q) {
                    v4f U0 = rb[(q*4 + 0)*64 + lane];
                    v4f U1 = rb[(q*4 + 1)*64 + lane];
                    v4f U2 = rb[(q*4 + 2)*64 + lane];
                    v4f U3 = rb[(q*4 + 3)*64 + lane];
                    float y0 = cstep(U0);
                    float y1 = cstep(U1);
                    float y2 = cstep(U2);
                    float y3 = cstep(U3);
                    if (u == 0) orow[(c - 1)*4 + q] = make_float4(y0, y1, y2, y3);
                    yprev = y3;
                }
            }
        }
        __syncthreads();
    }

    // ---- future loop: W1 only; flat tables + swizzle fstep (r17 verbatim) ----
    if (wid == 1) {
        v2f f1_if[10], f1_go[10], f2i_if[10], f2i_go[10], f2h_if[10], f2h_go[10];
        v2f wlp[5];
        #pragma unroll
        for (int j = 0; j < HID; ++j) {
            f1_if[j]  = mk2(sKm * Whh1[Ri*HID + j], sKm * Whh1[Rf*HID + j]);
            f1_go[j]  = mk2(tKm * Whh1[Rg*HID + j], sKm * Whh1[Ro*HID + j]);
            f2i_if[j] = mk2(sKm * Wih2[Ri*HID + j], sKm * Wih2[Rf*HID + j]);
            f2i_go[j] = mk2(tKm * Wih2[Rg*HID + j], sKm * Wih2[Ro*HID + j]);
            f2h_if[j] = mk2(sKm * Whh2[Ri*HID + j], sKm * Whh2[Rf*HID + j]);
            f2h_go[j] = mk2(tKm * Whh2[Rg*HID + j], sKm * Whh2[Ro*HID + j]);
        }
        #pragma unroll
        for (int k = 0; k < 5; ++k) wlp[k] = mk2(Wlin[2*k], Wlin[2*k + 1]);
        v2f fb1_if = mk2(sKm * (bih1[Ri] + bhh1[Ri]), sKm * (bih1[Rf] + bhh1[Rf]));
        v2f fb1_go = mk2(tKm * (bih1[Rg] + bhh1[Rg]), sKm * (bih1[Ro] + bhh1[Ro]));
        v2f fb2_if = mk2(sKm * (bih2[Ri] + bhh2[Ri]), sKm * (bih2[Rf] + bhh2[Rf]));
        v2f fb2_go = mk2(tKm * (bih2[Rg] + bhh2[Rg]), sKm * (bih2[Ro] + bhh2[Ro]));
        v2f fwx_if = mk2(sKm * Wih1[Ri], sKm * Wih1[Rf]);
        v2f fwx_go = mk2(tKm * Wih1[Rg], sKm * Wih1[Ro]);

        float h1b[10], h2b[10];
        c1 = stC1[lane];
        bcast10(stH1[lane], h1b);     // h1(T-1) flat (stores 2 barriers back)
        bcast10(h2r[0], h2b);         // own-lane h2 -> flat
        float yp = bc16<0>(yprev);    // uniform = exactly the stored y3

        auto head_ = [&]() -> float {
            v2f Y = pfma2(wlp[0], mk2(h2b[0], h2b[1]), mk2(bl, 0.f));
            #pragma unroll
            for (int k = 1; k < 5; ++k)
                Y = pfma2(wlp[k], mk2(h2b[2*k], h2b[2*k + 1]), Y);
            return Y.x + Y.y;
        };
        auto fstep = [&](float yt) -> float {
            v2f A_if = dotp(f1_if, h1b, pfma2(fwx_if, mk2(yt, yt), fb1_if));
            v2f A_go = dotp(f1_go, h1b, pfma2(fwx_go, mk2(yt, yt), fb1_go));
            float h1n = cellup2(A_if, A_go, c1);
            bcast10(h1n, h1b);
            v2f U_if = dotp(f2i_if, h1b, fb2_if);
            v2f U_go = dotp(f2i_go, h1b, fb2_go);
            v2f V_if = dotp(f2h_if, h2b, mk2(U_if.x, U_if.y));
            v2f V_go = dotp(f2h_go, h2b, mk2(U_go.x, U_go.y));
            float h2n = cellup2(V_if, V_go, c2);
            bcast10(h2n, h2b);
            return head_();
        };

        int t = 0;
        #pragma unroll 1
        for (; t + 3 < F; t += 4) {
            float y0 = fstep(yp);
            float y1 = fstep(y0);
            float y2 = fstep(y1);
            float y3 = fstep(y2);
            if (u == 0) orow[(TMAIN + t) / 4] = make_float4(y0, y1, y2, y3);
            yp = y3;
        }
        #pragma unroll 1
        for (; t < F; ++t) {
            yp = fstep(yp);
            if (u == 0) out[(size_t)ge * OUTW + TMAIN + t] = yp;
        }
    }
}

extern "C" void kernel_launch(void* const* d_in, const int* in_sizes, int n_in,
                              void* d_out, int out_size, void* d_ws, size_t ws_size,
                              hipStream_t stream) {
    const float* x    = (const float*)d_in[0];
    const float* Wih1 = (const float*)d_in[1];
    const float* Whh1 = (const float*)d_in[2];
    const float* bih1 = (const float*)d_in[3];
    const float* bhh1 = (const float*)d_in[4];
    const float* Wih2 = (const float*)d_in[5];
    const float* Whh2 = (const float*)d_in[6];
    const float* bih2 = (const float*)d_in[7];
    const float* bhh2 = (const float*)d_in[8];
    const float* Wlin = (const float*)d_in[9];
    const float* blin = (const float*)d_in[10];
    const int*   futp = (const int*)d_in[11];
    float* out = (float*)d_out;

    lstm2_kernel<<<NB, 128, 0, stream>>>(x, Wih1, Whh1, bih1, bhh1,
                                         Wih2, Whh2, bih2, bhh2,
                                         Wlin, blin, futp, out);
}